// Round 1
// baseline (3371.541 us; speedup 1.0000x reference)
//
#include <hip/hip_runtime.h>
#include <math.h>

// Problem constants (fixed by the reference)
#define N_NODES 50000
#define DIM     128
#define NHEAD   8
#define HDIM    16
#define NLAYER  2
#define NTYPE   4
#define NREL    8
#define NEDGE   800000
#define RB      256   // nodes per block for rank scan

// ---------------- rank-within-type init ----------------

__global__ void k_hist(const int* __restrict__ ntype, int* __restrict__ hist, int n) {
    __shared__ int cnt[NTYPE];
    if (threadIdx.x < NTYPE) cnt[threadIdx.x] = 0;
    __syncthreads();
    int i = blockIdx.x * RB + threadIdx.x;
    if (i < n) atomicAdd(&cnt[ntype[i]], 1);
    __syncthreads();
    if (threadIdx.x < NTYPE) hist[blockIdx.x * NTYPE + threadIdx.x] = cnt[threadIdx.x];
}

__global__ void k_prefix(const int* __restrict__ hist, int* __restrict__ off, int nb) {
    int t = threadIdx.x;
    if (t >= NTYPE) return;
    int acc = 0;
    for (int b = 0; b < nb; b++) { off[b * NTYPE + t] = acc; acc += hist[b * NTYPE + t]; }
}

__global__ void k_rank(const int* __restrict__ ntype, const int* __restrict__ off,
                       int* __restrict__ rank, int n) {
    __shared__ int ty[RB];
    int i = blockIdx.x * RB + threadIdx.x;
    int t = (i < n) ? ntype[i] : -1;
    ty[threadIdx.x] = t;
    __syncthreads();
    if (i < n) {
        int c = 0;
        for (int j = 0; j < (int)threadIdx.x; j++) c += (ty[j] == t);
        rank[i] = off[blockIdx.x * NTYPE + t] + c;
    }
}

__global__ void k_embed(const float* __restrict__ embed, const int* __restrict__ ntype,
                        const int* __restrict__ rank, float* __restrict__ h) {
    int i = blockIdx.x;
    int t = ntype[i], r = rank[i];
    h[(size_t)i * DIM + threadIdx.x] = embed[((size_t)t * N_NODES + r) * DIM + threadIdx.x];
}

// ---------------- typed k/q/v projection ----------------

__global__ __launch_bounds__(128) void k_qkv(
        const float* __restrict__ h, const int* __restrict__ ntype,
        const float* __restrict__ Wk, const float* __restrict__ Wq, const float* __restrict__ Wv,
        float* __restrict__ kout, float* __restrict__ qout, float* __restrict__ vout) {
    __shared__ float x[DIM];
    int i = blockIdx.x, o = threadIdx.x;
    x[o] = h[(size_t)i * DIM + o];
    __syncthreads();
    int t = ntype[i];
    const float* wk = Wk + (size_t)t * DIM * DIM;
    const float* wq = Wq + (size_t)t * DIM * DIM;
    const float* wv = Wv + (size_t)t * DIM * DIM;
    float ak = 0.f, aq = 0.f, av = 0.f;
    #pragma unroll 8
    for (int d = 0; d < DIM; d++) {
        float xv = x[d];
        ak = fmaf(xv, wk[d * DIM + o], ak);
        aq = fmaf(xv, wq[d * DIM + o], aq);
        av = fmaf(xv, wv[d * DIM + o], av);
    }
    kout[(size_t)i * DIM + o] = ak;
    qout[(size_t)i * DIM + o] = aq;
    vout[(size_t)i * DIM + o] = av;
}

// ---------------- edge attention logits + segment max ----------------
// 64 lanes per edge: lane = head*8 + j, each lane covers outputs {j, j+8}

__global__ __launch_bounds__(256) void k_edge_att(
        const float* __restrict__ kbuf, const float* __restrict__ qbuf,
        const int* __restrict__ src, const int* __restrict__ dst, const int* __restrict__ etype,
        const float* __restrict__ ratt, const float* __restrict__ rpri,
        float* __restrict__ a, unsigned int* __restrict__ amax) {
    int idx = blockIdx.x * blockDim.x + threadIdx.x;
    int e = idx >> 6;
    if (e >= NEDGE) return;
    int l = idx & 63;
    int hh = l >> 3, j = l & 7;
    int s = src[e], dn = dst[e], et = etype[e];
    const float* kr = kbuf + (size_t)s * DIM + hh * HDIM;
    const float* qr = qbuf + (size_t)dn * DIM + hh * HDIM;
    const float* w  = ratt + ((size_t)(hh * NREL + et) * HDIM) * HDIM;  // [d][o]
    float acc = 0.f;
    #pragma unroll
    for (int rep = 0; rep < 2; rep++) {
        int o = j + rep * 8;
        float kw = 0.f;
        #pragma unroll
        for (int d = 0; d < HDIM; d++) kw = fmaf(kr[d], w[d * HDIM + o], kw);
        acc = fmaf(kw, qr[o], acc);
    }
    acc += __shfl_xor(acc, 1);
    acc += __shfl_xor(acc, 2);
    acc += __shfl_xor(acc, 4);
    if (j == 0) {
        float av = acc * rpri[hh * NREL + et] * 0.25f;  // / sqrt(16)
        a[(size_t)e * NHEAD + hh] = av;
        unsigned int u = __float_as_uint(av);
        u = (u & 0x80000000u) ? ~u : (u | 0x80000000u);  // monotonic float->uint
        atomicMax(&amax[dn * NHEAD + hh], u);
    }
}

// ---------------- exp + segment sum ----------------

__global__ __launch_bounds__(256) void k_edge_exp(
        float* __restrict__ a, const int* __restrict__ dst,
        const unsigned int* __restrict__ amax, float* __restrict__ ssum) {
    int idx = blockIdx.x * blockDim.x + threadIdx.x;
    if (idx >= NEDGE * NHEAD) return;
    int e = idx >> 3, hh = idx & 7;
    int dn = dst[e];
    unsigned int u = amax[dn * NHEAD + hh];
    unsigned int ub = (u & 0x80000000u) ? (u & 0x7fffffffu) : ~u;
    float mx = __uint_as_float(ub);
    float ex = __expf(a[idx] - mx);
    a[idx] = ex;
    atomicAdd(&ssum[dn * NHEAD + hh], ex);
}

// ---------------- message transform + weighted aggregation ----------------

__global__ __launch_bounds__(256) void k_edge_msg(
        const float* __restrict__ vbuf, const float* __restrict__ ex, const float* __restrict__ ssum,
        const int* __restrict__ src, const int* __restrict__ dst, const int* __restrict__ etype,
        const float* __restrict__ rmsg, float* __restrict__ agg) {
    int idx = blockIdx.x * blockDim.x + threadIdx.x;
    int e = idx >> 6;
    if (e >= NEDGE) return;
    int l = idx & 63;
    int hh = l >> 3, j = l & 7;
    int s = src[e], dn = dst[e], et = etype[e];
    const float* vr = vbuf + (size_t)s * DIM + hh * HDIM;
    const float* w  = rmsg + ((size_t)(hh * NREL + et) * HDIM) * HDIM;
    float att = ex[(size_t)e * NHEAD + hh] / (ssum[dn * NHEAD + hh] + 1e-9f);
    #pragma unroll
    for (int rep = 0; rep < 2; rep++) {
        int o = j + rep * 8;
        float m = 0.f;
        #pragma unroll
        for (int d = 0; d < HDIM; d++) m = fmaf(vr[d], w[d * HDIM + o], m);
        atomicAdd(&agg[(size_t)dn * DIM + hh * HDIM + o], m * att);
    }
}

// ---------------- output projection + skip + LayerNorm + residual ----------------

__global__ __launch_bounds__(128) void k_out(
        const float* __restrict__ agg, float* __restrict__ h,
        const int* __restrict__ ntype, const float* __restrict__ Wa,
        const float* __restrict__ skip, const float* __restrict__ ln_g,
        const float* __restrict__ ln_b) {
    __shared__ float x[DIM];
    __shared__ float wsum[2];
    int i = blockIdx.x, o = threadIdx.x;
    x[o] = agg[(size_t)i * DIM + o];
    __syncthreads();
    int t = ntype[i];
    const float* w = Wa + (size_t)t * DIM * DIM;
    float acc = 0.f;
    #pragma unroll 8
    for (int d = 0; d < DIM; d++) acc = fmaf(x[d], w[d * DIM + o], acc);
    float alpha = 1.f / (1.f + __expf(-skip[t]));
    float hp = h[(size_t)i * DIM + o];
    float hc = acc * alpha + hp * (1.f - alpha);
    // LayerNorm over 128 (2 waves)
    float s = hc;
    #pragma unroll
    for (int m = 1; m < 64; m <<= 1) s += __shfl_xor(s, m);
    if ((o & 63) == 0) wsum[o >> 6] = s;
    __syncthreads();
    float mu = (wsum[0] + wsum[1]) * (1.0f / DIM);
    __syncthreads();
    float dv = hc - mu;
    float vs = dv * dv;
    #pragma unroll
    for (int m = 1; m < 64; m <<= 1) vs += __shfl_xor(vs, m);
    if ((o & 63) == 0) wsum[o >> 6] = vs;
    __syncthreads();
    float var = (wsum[0] + wsum[1]) * (1.0f / DIM);
    float res = dv * rsqrtf(var + 1e-5f) * ln_g[o] + ln_b[o] + hp;
    h[(size_t)i * DIM + o] = res;
}

// ---------------- host ----------------

extern "C" void kernel_launch(void* const* d_in, const int* in_sizes, int n_in,
                              void* d_out, int out_size, void* d_ws, size_t ws_size,
                              hipStream_t stream) {
    const float* embed = (const float*)d_in[0];
    const float* Wk    = (const float*)d_in[1];
    const float* Wq    = (const float*)d_in[2];
    const float* Wv    = (const float*)d_in[3];
    const float* Wa    = (const float*)d_in[4];
    const float* ratt  = (const float*)d_in[5];
    const float* rmsg  = (const float*)d_in[6];
    const float* rpri  = (const float*)d_in[7];
    const float* skip  = (const float*)d_in[8];
    const float* ln_g  = (const float*)d_in[9];
    const float* ln_b  = (const float*)d_in[10];
    const int*   src   = (const int*)d_in[11];
    const int*   dst   = (const int*)d_in[12];
    const int*   ntype = (const int*)d_in[13];
    const int*   etype = (const int*)d_in[14];

    float* h = (float*)d_out;   // h lives in d_out; updated in place per layer

    const size_t ND = (size_t)N_NODES * DIM;
    const size_t EH = (size_t)NEDGE * NHEAD;
    float* kbuf = (float*)d_ws;
    float* qbuf = kbuf + ND;          // aliased: agg reuses qbuf after attention pass
    float* vbuf = qbuf + ND;
    float* abuf = vbuf + ND;          // (E,H) logits, then exp
    unsigned int* amax = (unsigned int*)(abuf + EH);
    float* ssum = (float*)(amax + (size_t)N_NODES * NHEAD);
    int* rank = (int*)(ssum + (size_t)N_NODES * NHEAD);
    int* hist = rank + N_NODES;
    const int nb = (N_NODES + RB - 1) / RB;
    int* boff = hist + (size_t)nb * NTYPE;
    float* agg = qbuf;

    // init: rank within type, embed gather
    k_hist<<<nb, RB, 0, stream>>>(ntype, hist, N_NODES);
    k_prefix<<<1, 64, 0, stream>>>(hist, boff, nb);
    k_rank<<<nb, RB, 0, stream>>>(ntype, boff, rank, N_NODES);
    k_embed<<<N_NODES, DIM, 0, stream>>>(embed, ntype, rank, h);

    for (int l = 0; l < NLAYER; l++) {
        const float* Wk_l = Wk + (size_t)l * NTYPE * DIM * DIM;
        const float* Wq_l = Wq + (size_t)l * NTYPE * DIM * DIM;
        const float* Wv_l = Wv + (size_t)l * NTYPE * DIM * DIM;
        const float* Wa_l = Wa + (size_t)l * NTYPE * DIM * DIM;
        const float* ratt_l = ratt + (size_t)l * NHEAD * NREL * HDIM * HDIM;
        const float* rmsg_l = rmsg + (size_t)l * NHEAD * NREL * HDIM * HDIM;
        const float* rpri_l = rpri + (size_t)l * NHEAD * NREL;
        const float* skip_l = skip + (size_t)l * NTYPE;
        const float* g_l = ln_g + (size_t)l * DIM;
        const float* b_l = ln_b + (size_t)l * DIM;

        hipMemsetAsync(amax, 0, (size_t)N_NODES * NHEAD * 4, stream);
        hipMemsetAsync(ssum, 0, (size_t)N_NODES * NHEAD * 4, stream);

        k_qkv<<<N_NODES, DIM, 0, stream>>>(h, ntype, Wk_l, Wq_l, Wv_l, kbuf, qbuf, vbuf);
        k_edge_att<<<(NEDGE * 64) / 256, 256, 0, stream>>>(kbuf, qbuf, src, dst, etype,
                                                           ratt_l, rpri_l, abuf, amax);
        hipMemsetAsync(agg, 0, ND * 4, stream);  // agg aliases qbuf (q dead after att)
        k_edge_exp<<<(NEDGE * NHEAD) / 256, 256, 0, stream>>>(abuf, dst, amax, ssum);
        k_edge_msg<<<(NEDGE * 64) / 256, 256, 0, stream>>>(vbuf, abuf, ssum, src, dst, etype,
                                                           rmsg_l, agg);
        k_out<<<N_NODES, DIM, 0, stream>>>(agg, h, ntype, Wa_l, skip_l, g_l, b_l);
    }
}

// Round 2
// 1329.289 us; speedup vs baseline: 2.5363x; 2.5363x over previous
//
#include <hip/hip_runtime.h>
#include <math.h>

#define N_NODES 50000
#define DIM     128
#define NHEAD   8
#define HDIM    16
#define NLAYER  2
#define NTYPE   4
#define NREL    8
#define NEDGE   800000
#define RB      256
#define GN      8      // nodes per block in grouped qkv/out kernels (50000/8 = 6250 exact)
#define CHUNK   32     // edges per chunk in fused kernel

// ================= init: rank within type =================

__global__ void k_hist(const int* __restrict__ ntype, int* __restrict__ hist, int n) {
    __shared__ int cnt[NTYPE];
    if (threadIdx.x < NTYPE) cnt[threadIdx.x] = 0;
    __syncthreads();
    int i = blockIdx.x * RB + threadIdx.x;
    if (i < n) atomicAdd(&cnt[ntype[i]], 1);
    __syncthreads();
    if (threadIdx.x < NTYPE) hist[blockIdx.x * NTYPE + threadIdx.x] = cnt[threadIdx.x];
}

__global__ void k_prefix(const int* __restrict__ hist, int* __restrict__ off, int nb) {
    int t = threadIdx.x;
    if (t >= NTYPE) return;
    int acc = 0;
    for (int b = 0; b < nb; b++) { off[b * NTYPE + t] = acc; acc += hist[b * NTYPE + t]; }
}

__global__ void k_rank(const int* __restrict__ ntype, const int* __restrict__ off,
                       int* __restrict__ rank, int n) {
    __shared__ int ty[RB];
    int i = blockIdx.x * RB + threadIdx.x;
    int t = (i < n) ? ntype[i] : -1;
    ty[threadIdx.x] = t;
    __syncthreads();
    if (i < n) {
        int c = 0;
        for (int j = 0; j < (int)threadIdx.x; j++) c += (ty[j] == t);
        rank[i] = off[blockIdx.x * NTYPE + t] + c;
    }
}

__global__ void k_embed(const float* __restrict__ embed, const int* __restrict__ ntype,
                        const int* __restrict__ rank, float* __restrict__ h) {
    int i = blockIdx.x;
    int t = ntype[i], r = rank[i];
    h[(size_t)i * DIM + threadIdx.x] = embed[((size_t)t * N_NODES + r) * DIM + threadIdx.x];
}

__global__ void k_typeoff(const int* __restrict__ hist, const int* __restrict__ boff,
                          int nb, int* __restrict__ typeoff) {
    if (threadIdx.x == 0 && blockIdx.x == 0) {
        int acc = 0;
        for (int t = 0; t < NTYPE; t++) {
            typeoff[t] = acc;
            acc += boff[(nb - 1) * NTYPE + t] + hist[(nb - 1) * NTYPE + t];
        }
    }
}

__global__ void k_perm(const int* __restrict__ ntype, const int* __restrict__ rank,
                       const int* __restrict__ typeoff, int* __restrict__ perm, int n) {
    int i = blockIdx.x * 256 + threadIdx.x;
    if (i < n) perm[typeoff[ntype[i]] + rank[i]] = i;
}

// ================= CSR build (dst-sorted edges) =================

__global__ void k_deg(const int* __restrict__ dst, int* __restrict__ deg) {
    int e = blockIdx.x * 256 + threadIdx.x;
    if (e < NEDGE) atomicAdd(&deg[dst[e]], 1);
}

__global__ void k_scan1(const int* __restrict__ deg, int* __restrict__ rs,
                        int* __restrict__ bsum, int n) {
    __shared__ int sh[256];
    int i = blockIdx.x * 256 + threadIdx.x;
    int v = (i < n) ? deg[i] : 0;
    sh[threadIdx.x] = v;
    __syncthreads();
    for (int off = 1; off < 256; off <<= 1) {
        int x = (threadIdx.x >= off) ? sh[threadIdx.x - off] : 0;
        __syncthreads();
        sh[threadIdx.x] += x;
        __syncthreads();
    }
    if (i < n) rs[i] = sh[threadIdx.x] - v;            // exclusive within block
    if (threadIdx.x == 255) bsum[blockIdx.x] = sh[255];
}

__global__ void k_scan2(int* __restrict__ bsum, int nb) {
    __shared__ int sh[256];
    int t = threadIdx.x;
    int v = (t < nb) ? bsum[t] : 0;
    sh[t] = v;
    __syncthreads();
    for (int off = 1; off < 256; off <<= 1) {
        int x = (t >= off) ? sh[t - off] : 0;
        __syncthreads();
        sh[t] += x;
        __syncthreads();
    }
    if (t < nb) bsum[t] = sh[t] - v;                    // exclusive
}

__global__ void k_scan3(int* __restrict__ rs, const int* __restrict__ bsum, int n) {
    int i = blockIdx.x * 256 + threadIdx.x;
    if (i < n) rs[i] += bsum[blockIdx.x];
    if (i == 0) rs[n] = NEDGE;
}

__global__ void k_scatter(const int* __restrict__ dst, const int* __restrict__ rs,
                          int* __restrict__ cur, int* __restrict__ eidx) {
    int e = blockIdx.x * 256 + threadIdx.x;
    if (e < NEDGE) {
        int d = dst[e];
        int p = atomicAdd(&cur[d], 1);
        eidx[rs[d] + p] = e;
    }
}

// ================= typed k/q/v projection, 8 same-type nodes/block =================

__global__ __launch_bounds__(128) void k_qkv_g(
        const float* __restrict__ h, const int* __restrict__ perm, const int* __restrict__ ntype,
        const float* __restrict__ Wk, const float* __restrict__ Wq, const float* __restrict__ Wv,
        float* __restrict__ kout, float* __restrict__ qout, float* __restrict__ vout, int n) {
    int o = threadIdx.x;
    int base = blockIdx.x * GN;
    __shared__ float xs[GN][DIM];
    __shared__ int nodes[GN];
    __shared__ int types[GN];
    if (o < GN) {
        int idx = base + o;
        int nd = (idx < n) ? perm[idx] : -1;
        nodes[o] = nd;
        types[o] = (nd >= 0) ? ntype[nd] : -1;
    }
    __syncthreads();
    #pragma unroll
    for (int nn = 0; nn < GN; nn++)
        if (nodes[nn] >= 0) xs[nn][o] = h[(size_t)nodes[nn] * DIM + o];
    __syncthreads();
    bool same = (nodes[GN - 1] >= 0) && (types[0] == types[GN - 1]);
    if (same) {
        int t = types[0];
        const float* wk = Wk + (size_t)t * DIM * DIM;
        const float* wq = Wq + (size_t)t * DIM * DIM;
        const float* wv = Wv + (size_t)t * DIM * DIM;
        float ak[GN], aq[GN], av[GN];
        #pragma unroll
        for (int nn = 0; nn < GN; nn++) { ak[nn] = 0.f; aq[nn] = 0.f; av[nn] = 0.f; }
        for (int d = 0; d < DIM; d++) {
            float wkv = wk[d * DIM + o], wqv = wq[d * DIM + o], wvv = wv[d * DIM + o];
            #pragma unroll
            for (int nn = 0; nn < GN; nn++) {
                float xv = xs[nn][d];
                ak[nn] = fmaf(xv, wkv, ak[nn]);
                aq[nn] = fmaf(xv, wqv, aq[nn]);
                av[nn] = fmaf(xv, wvv, av[nn]);
            }
        }
        #pragma unroll
        for (int nn = 0; nn < GN; nn++) {
            size_t p = (size_t)nodes[nn] * DIM + o;
            kout[p] = ak[nn]; qout[p] = aq[nn]; vout[p] = av[nn];
        }
    } else {
        #pragma unroll
        for (int nn = 0; nn < GN; nn++) {
            if (nodes[nn] < 0) continue;
            int t = types[nn];
            const float* wk = Wk + (size_t)t * DIM * DIM;
            const float* wq = Wq + (size_t)t * DIM * DIM;
            const float* wv = Wv + (size_t)t * DIM * DIM;
            float ak = 0.f, aq = 0.f, av = 0.f;
            for (int d = 0; d < DIM; d++) {
                float xv = xs[nn][d];
                ak = fmaf(xv, wk[d * DIM + o], ak);
                aq = fmaf(xv, wq[d * DIM + o], aq);
                av = fmaf(xv, wv[d * DIM + o], av);
            }
            size_t p = (size_t)nodes[nn] * DIM + o;
            kout[p] = ak; qout[p] = aq; vout[p] = av;
        }
    }
}

// ================= fused per-dst-node attention + softmax + aggregation =================
// Block = 128 threads, one dst node. thread = (hh = tid>>4, oo = tid&15).
// a_e,h = k_src · (W_att,h,et · q_dst,h) * pri * 0.25   (u precomputed per node)
// h_out = [ sum_et (sum_{e in et} p_e v_e) · W_msg,et ] / (s + 1e-9)

__global__ __launch_bounds__(128) void k_fused(
        const float* __restrict__ kbuf, const float* __restrict__ qbuf, const float* __restrict__ vbuf,
        const int* __restrict__ row_start, const int* __restrict__ eidx,
        const int* __restrict__ src, const int* __restrict__ etype,
        const float* __restrict__ ratt, const float* __restrict__ rmsg, const float* __restrict__ rpri,
        float* __restrict__ agg) {
    int node = blockIdx.x;
    int tid = threadIdx.x;
    int hh = tid >> 4, oo = tid & 15;
    __shared__ float q_s[DIM];
    __shared__ float u_s[NREL][NHEAD][HDIM];     // (W_att q) per etype, pri/sqrt_d folded in
    __shared__ float accv[NREL][NHEAD][HDIM];    // etype-bucketed p-weighted v sums
    __shared__ float a_s[CHUNK][NHEAD + 1];      // +1 pad: kill 4-way bank conflict
    __shared__ int es_s[CHUNK];
    __shared__ int et_s[CHUNK];
    __shared__ float pri_s[NHEAD][NREL];

    q_s[tid] = qbuf[(size_t)node * DIM + tid];
    if (tid < NHEAD * NREL) pri_s[tid >> 3][tid & 7] = rpri[tid];
    __syncthreads();

    // u_s[et][hh][d] = (sum_o ratt[hh][et][d][o] * q[hh*16+o]) * pri * 0.25 ; thread d = oo
    #pragma unroll
    for (int et = 0; et < NREL; et++) {
        const float* w = ratt + ((size_t)(hh * NREL + et) * HDIM + oo) * HDIM;
        float s = 0.f;
        #pragma unroll
        for (int o = 0; o < HDIM; o++) s = fmaf(w[o], q_s[hh * HDIM + o], s);
        u_s[et][hh][oo] = s * pri_s[hh][et] * 0.25f;
        accv[et][hh][oo] = 0.f;
    }
    __syncthreads();

    int e0 = row_start[node], e1 = row_start[node + 1];
    float m_h = -1e30f, s_h = 0.f;   // replicated across each 16-lane head group

    for (int base = e0; base < e1; base += CHUNK) {
        int cnt = min(CHUNK, e1 - base);
        if (tid < cnt) {
            int e = eidx[base + tid];
            es_s[tid] = src[e];
            et_s[tid] = etype[e];
        }
        __syncthreads();
        // logits for this chunk: thread (hh,oo) covers edges c = oo, oo+16
        for (int c = oo; c < cnt; c += 16) {
            int s = es_s[c], et = et_s[c];
            const float* kr = kbuf + (size_t)s * DIM + hh * HDIM;
            const float* u = &u_s[et][hh][0];
            float a = 0.f;
            #pragma unroll
            for (int d = 0; d < HDIM; d++) a = fmaf(kr[d], u[d], a);
            a_s[c][hh] = a;
        }
        __syncthreads();
        // online softmax update, per 16-lane head group
        float cmax = -1e30f;
        for (int c = oo; c < cnt; c += 16) cmax = fmaxf(cmax, a_s[c][hh]);
        #pragma unroll
        for (int m = 1; m < 16; m <<= 1) cmax = fmaxf(cmax, __shfl_xor(cmax, m));
        float m_new = fmaxf(m_h, cmax);
        float r = __expf(m_h - m_new);
        float csum = 0.f;
        for (int c = oo; c < cnt; c += 16) {
            float p = __expf(a_s[c][hh] - m_new);
            a_s[c][hh] = p;
            csum += p;
        }
        #pragma unroll
        for (int m = 1; m < 16; m <<= 1) csum += __shfl_xor(csum, m);
        s_h = s_h * r + csum;
        m_h = m_new;
        // rescale buckets (thread owns accv[*][hh][oo])
        #pragma unroll
        for (int et = 0; et < NREL; et++) accv[et][hh][oo] *= r;
        __syncthreads();
        // bucket p-weighted v: thread (hh, d=oo); coalesced v row reads per edge
        for (int c = 0; c < cnt; c++) {
            int s = es_s[c], et = et_s[c];
            float p = a_s[c][hh];
            float vv = vbuf[(size_t)s * DIM + hh * HDIM + oo];
            accv[et][hh][oo] += p * vv;
        }
        __syncthreads();
    }

    // apply W_msg once per node: out[hh][oo] = sum_et sum_d accv[et][hh][d]*rmsg[hh][et][d][oo]
    float out = 0.f;
    #pragma unroll
    for (int et = 0; et < NREL; et++) {
        const float* w = rmsg + ((size_t)(hh * NREL + et) * HDIM) * HDIM;
        #pragma unroll
        for (int d = 0; d < HDIM; d++) out = fmaf(accv[et][hh][d], w[d * HDIM + oo], out);
    }
    agg[(size_t)node * DIM + tid] = out / (s_h + 1e-9f);
}

// ================= output projection + skip + LayerNorm + residual, grouped =================

__global__ __launch_bounds__(128) void k_out_g(
        const float* __restrict__ agg, float* __restrict__ h,
        const int* __restrict__ perm, const int* __restrict__ ntype,
        const float* __restrict__ Wa, const float* __restrict__ skip,
        const float* __restrict__ ln_g, const float* __restrict__ ln_b, int n) {
    int o = threadIdx.x;
    int base = blockIdx.x * GN;
    __shared__ float xs[GN][DIM];
    __shared__ float hcs[GN][DIM + 1];
    __shared__ int nodes[GN];
    __shared__ int types[GN];
    __shared__ float mu_s[GN], rs_s[GN];
    if (o < GN) {
        int idx = base + o;
        int nd = (idx < n) ? perm[idx] : -1;
        nodes[o] = nd;
        types[o] = (nd >= 0) ? ntype[nd] : -1;
    }
    __syncthreads();
    #pragma unroll
    for (int nn = 0; nn < GN; nn++)
        if (nodes[nn] >= 0) xs[nn][o] = agg[(size_t)nodes[nn] * DIM + o];
    __syncthreads();
    bool same = (nodes[GN - 1] >= 0) && (types[0] == types[GN - 1]);
    if (same) {
        int t = types[0];
        const float* w = Wa + (size_t)t * DIM * DIM;
        float acc[GN];
        #pragma unroll
        for (int nn = 0; nn < GN; nn++) acc[nn] = 0.f;
        for (int d = 0; d < DIM; d++) {
            float wv = w[d * DIM + o];
            #pragma unroll
            for (int nn = 0; nn < GN; nn++) acc[nn] = fmaf(xs[nn][d], wv, acc[nn]);
        }
        float alpha = 1.f / (1.f + __expf(-skip[t]));
        #pragma unroll
        for (int nn = 0; nn < GN; nn++) {
            float hp = h[(size_t)nodes[nn] * DIM + o];
            hcs[nn][o] = acc[nn] * alpha + hp * (1.f - alpha);
        }
    } else {
        #pragma unroll
        for (int nn = 0; nn < GN; nn++) {
            if (nodes[nn] < 0) continue;
            int t = types[nn];
            const float* w = Wa + (size_t)t * DIM * DIM;
            float a0 = 0.f;
            for (int d = 0; d < DIM; d++) a0 = fmaf(xs[nn][d], w[d * DIM + o], a0);
            float alpha = 1.f / (1.f + __expf(-skip[t]));
            float hp = h[(size_t)nodes[nn] * DIM + o];
            hcs[nn][o] = a0 * alpha + hp * (1.f - alpha);
        }
    }
    __syncthreads();
    // LayerNorm stats: 16-lane group g handles node g
    {
        int g = o >> 4, j = o & 15;
        if (nodes[g] >= 0) {
            float s = 0.f;
            for (int d = j; d < DIM; d += 16) s += hcs[g][d];
            #pragma unroll
            for (int m = 1; m < 16; m <<= 1) s += __shfl_xor(s, m);
            float mu = s * (1.f / DIM);
            float v = 0.f;
            for (int d = j; d < DIM; d += 16) { float dv = hcs[g][d] - mu; v = fmaf(dv, dv, v); }
            #pragma unroll
            for (int m = 1; m < 16; m <<= 1) v += __shfl_xor(v, m);
            if (j == 0) { mu_s[g] = mu; rs_s[g] = rsqrtf(v * (1.f / DIM) + 1e-5f); }
        }
    }
    __syncthreads();
    float g_o = ln_g[o], b_o = ln_b[o];
    #pragma unroll
    for (int nn = 0; nn < GN; nn++) {
        if (nodes[nn] >= 0) {
            float hp = h[(size_t)nodes[nn] * DIM + o];
            h[(size_t)nodes[nn] * DIM + o] = (hcs[nn][o] - mu_s[nn]) * rs_s[nn] * g_o + b_o + hp;
        }
    }
}

// ================= host =================

extern "C" void kernel_launch(void* const* d_in, const int* in_sizes, int n_in,
                              void* d_out, int out_size, void* d_ws, size_t ws_size,
                              hipStream_t stream) {
    const float* embed = (const float*)d_in[0];
    const float* Wk    = (const float*)d_in[1];
    const float* Wq    = (const float*)d_in[2];
    const float* Wv    = (const float*)d_in[3];
    const float* Wa    = (const float*)d_in[4];
    const float* ratt  = (const float*)d_in[5];
    const float* rmsg  = (const float*)d_in[6];
    const float* rpri  = (const float*)d_in[7];
    const float* skip  = (const float*)d_in[8];
    const float* ln_g  = (const float*)d_in[9];
    const float* ln_b  = (const float*)d_in[10];
    const int*   src   = (const int*)d_in[11];
    const int*   dst   = (const int*)d_in[12];
    const int*   ntype = (const int*)d_in[13];
    const int*   etype = (const int*)d_in[14];

    float* h = (float*)d_out;

    const size_t ND = (size_t)N_NODES * DIM;
    float* kbuf = (float*)d_ws;
    float* qbuf = kbuf + ND;
    float* vbuf = qbuf + ND;
    int* row_start = (int*)(vbuf + ND);          // N+1
    int* deg  = row_start + (N_NODES + 1);       // N
    int* cur  = deg + N_NODES;                   // N
    int* eidx = cur + N_NODES;                   // E
    int* bsum = eidx + NEDGE;                    // 256
    int* rank = bsum + 256;                      // N
    const int nb = (N_NODES + RB - 1) / RB;      // 196
    int* hist = rank + N_NODES;                  // nb*NTYPE
    int* boff = hist + nb * NTYPE;               // nb*NTYPE
    int* typeoff = boff + nb * NTYPE;            // NTYPE
    int* perm = typeoff + NTYPE;                 // N
    float* agg = qbuf;                           // alias: q dead once fused block read its row

    const int EB = (NEDGE + 255) / 256;

    // ---- init: rank-within-type, embedding, type permutation ----
    k_hist<<<nb, RB, 0, stream>>>(ntype, hist, N_NODES);
    k_prefix<<<1, 64, 0, stream>>>(hist, boff, nb);
    k_rank<<<nb, RB, 0, stream>>>(ntype, boff, rank, N_NODES);
    k_embed<<<N_NODES, DIM, 0, stream>>>(embed, ntype, rank, h);
    k_typeoff<<<1, 64, 0, stream>>>(hist, boff, nb, typeoff);
    k_perm<<<nb, 256, 0, stream>>>(ntype, rank, typeoff, perm, N_NODES);

    // ---- CSR build (once; graph static across layers) ----
    hipMemsetAsync(deg, 0, N_NODES * sizeof(int), stream);
    hipMemsetAsync(cur, 0, N_NODES * sizeof(int), stream);
    k_deg<<<EB, 256, 0, stream>>>(dst, deg);
    k_scan1<<<nb, 256, 0, stream>>>(deg, row_start, bsum, N_NODES);
    k_scan2<<<1, 256, 0, stream>>>(bsum, nb);
    k_scan3<<<nb, 256, 0, stream>>>(row_start, bsum, N_NODES);
    k_scatter<<<EB, 256, 0, stream>>>(dst, row_start, cur, eidx);

    const int NGB = N_NODES / GN;  // 6250 exact

    for (int l = 0; l < NLAYER; l++) {
        const float* Wk_l = Wk + (size_t)l * NTYPE * DIM * DIM;
        const float* Wq_l = Wq + (size_t)l * NTYPE * DIM * DIM;
        const float* Wv_l = Wv + (size_t)l * NTYPE * DIM * DIM;
        const float* Wa_l = Wa + (size_t)l * NTYPE * DIM * DIM;
        const float* ratt_l = ratt + (size_t)l * NHEAD * NREL * HDIM * HDIM;
        const float* rmsg_l = rmsg + (size_t)l * NHEAD * NREL * HDIM * HDIM;
        const float* rpri_l = rpri + (size_t)l * NHEAD * NREL;
        const float* skip_l = skip + (size_t)l * NTYPE;
        const float* g_l = ln_g + (size_t)l * DIM;
        const float* b_l = ln_b + (size_t)l * DIM;

        k_qkv_g<<<NGB, 128, 0, stream>>>(h, perm, ntype, Wk_l, Wq_l, Wv_l,
                                         kbuf, qbuf, vbuf, N_NODES);
        k_fused<<<N_NODES, 128, 0, stream>>>(kbuf, qbuf, vbuf, row_start, eidx,
                                             src, etype, ratt_l, rmsg_l, rpri_l, agg);
        k_out_g<<<NGB, 128, 0, stream>>>(agg, h, perm, ntype, Wa_l, skip_l, g_l, b_l, N_NODES);
    }
}